// Round 5
// baseline (167.141 us; speedup 1.0000x reference)
//
#include <hip/hip_runtime.h>
#include <type_traits>

#define RES_ 0.16f
#define XMIN_ -51.2f
#define YMIN_ -51.2f
#define EPS_ 1e-5f
#define NEG_ -1000000000.0f

#define WPB 4  // waves per block

typedef _Float16 f16x8 __attribute__((ext_vector_type(8)));
typedef _Float16 f16x4 __attribute__((ext_vector_type(4)));
typedef _Float16 f16x2 __attribute__((ext_vector_type(2)));
typedef float f32x4 __attribute__((ext_vector_type(4)));

union F8u { f16x8 v; f16x2 h[4]; };
union F4u { f16x4 v; f16x2 h[2]; };

static __device__ __forceinline__ f16x2 pkrtz(float a, float b) {
    return __builtin_bit_cast(f16x2, __builtin_amdgcn_cvt_pkrtz(a, b));
}

static __device__ __forceinline__ f16x2 relu2(f16x2 x) {
#if __has_builtin(__builtin_elementwise_max)
    const f16x2 z2 = (f16x2)(_Float16)0.f;
    return __builtin_elementwise_max(x, z2);   // v_pk_max_f16
#else
    f16x2 r;
    r[0] = x[0] > (_Float16)0.f ? x[0] : (_Float16)0.f;
    r[1] = x[1] > (_Float16)0.f ? x[1] : (_Float16)0.f;
    return r;
#endif
}

static __device__ __forceinline__ float fast_rcp(float x) {
#if __has_builtin(__builtin_amdgcn_rcpf)
    return __builtin_amdgcn_rcpf(x);
#else
    return 1.0f / x;
#endif
}

// DPP row_ror add — pure-VALU cross-lane sum within each 16-lane row.
template <int CTRL>
static __device__ __forceinline__ float dpp_ror_add(float x) {
    int r = __builtin_amdgcn_update_dpp(0, __float_as_int(x), CTRL, 0xf, 0xf, true);
    return x + __int_as_float(r);
}

// xor16 / xor32 max via gfx950 VALU cross-lane swaps (zero DS traffic).
static __device__ __forceinline__ float xmax16(float x) {
    float a = x, b = x;
    asm("v_permlane16_swap_b32 %0, %1" : "+v"(a), "+v"(b));
    return fmaxf(a, b);
}
static __device__ __forceinline__ float xmax32(float x) {
    float a = x, b = x;
    asm("v_permlane32_swap_b32 %0, %1" : "+v"(a), "+v"(b));
    return fmaxf(a, b);
}

// NOTE (r11): zero-LDS dataflow — layer-1 transposed (W1^T @ feat^T); its MFMA
// C-output IS layer-2's A-operand under W2 k-row perm c=32kt+16(j>>2)+4q+(j&3).
// NOTE (r9/r12/r14 PIN): launch_bounds TIGHTER than (256,4) spills (allocator
// cap < demand). Loosening is safe; tightening is not.
// NOTE (r15 PIN): grid 2048 did NOT raise occupancy (33->34%) — residency is
// hard-capped ~4 waves/SIMD by TOTAL unified VGPR (~120; VGPR_Count=52 is
// arch-only). TLP is capped -> ILP is the lever.
// NOTE (r16/r17): all cross-lane on VALU (DPP ror-add, permlane swaps). This
// was NEUTRAL (57.5->59us) — lgkm-poisoning theory falsified. Kept (cheaper,
// -4 VGPR).
// NOTE (r18, this round): PAIR processing — 2 pillars per wave iteration,
// chains manually interleaved (8 indep layer-1 MFMAs back-to-back, paired
// layer-2, dual zreduce). Halves exposed dependency latency per pillar.
// launch_bounds (256,3) to give the allocator headroom (~170 cap) for the
// ~+40-reg second pillar state. Tripwire: WRITE_SIZE == 25000 KB.
__global__ __launch_bounds__(256, 3) void pfn_kernel(
    const float* __restrict__ pillars,
    const int* __restrict__ coords,
    const int* __restrict__ npts_arr,
    const float* __restrict__ W1, const float* __restrict__ b1,
    const float* __restrict__ g1, const float* __restrict__ beta1,
    const float* __restrict__ m1, const float* __restrict__ v1,
    const float* __restrict__ W2, const float* __restrict__ b2,
    const float* __restrict__ g2, const float* __restrict__ beta2,
    const float* __restrict__ m2, const float* __restrict__ v2,
    float* __restrict__ out, int P)
{
    const int tid  = threadIdx.x;
    const int wave = tid >> 6;
    const int lane = tid & 63;
    const int quad = lane >> 4;
    const int col  = lane & 15;

    // ---- W1^T as layer-1 A-frags (K padded 9->16), BN1 folded ----
    f16x4 aw1[4];
#pragma unroll
    for (int mt = 0; mt < 4; ++mt) {
        const int ch = mt * 16 + col;
        const float a1 = g1[ch] * rsqrtf(v1[ch] + EPS_);
        const float c1 = fmaf(a1, b1[ch] - m1[ch], beta1[ch]);
#pragma unroll
        for (int j = 0; j < 4; ++j) {
            const int k = quad * 4 + j;
            float w;
            if (k < 9)        w = a1 * W1[k * 64 + ch];
            else if (k == 9)  w = c1;                      // bias slot (feat=1.0)
            else if (k == 10) w = a1 * W1[6 * 64 + ch];    // z_mean slot (feat=-zm)
            else              w = 0.0f;
            aw1[mt][j] = (_Float16)w;
        }
    }

    // ---- W2 (BN2-scale folded), k-rows permuted ----
    f16x8 bw2[2][4];
#pragma unroll
    for (int nt = 0; nt < 4; ++nt) {
        const int n0 = nt * 16 + col;
        const float a2 = g2[n0] * rsqrtf(v2[n0] + EPS_);
#pragma unroll
        for (int kt = 0; kt < 2; ++kt)
#pragma unroll
            for (int j = 0; j < 8; ++j) {
                const int c = 32 * kt + 16 * (j >> 2) + 4 * quad + (j & 3);
                bw2[kt][nt][j] = (_Float16)(a2 * W2[c * 64 + n0]);
            }
    }
    const float c2own = fmaf(g2[lane] * rsqrtf(v2[lane] + EPS_),
                             b2[lane] - m2[lane], beta2[lane]);

    auto zreduce = [&](const float4& A, const float4& B, int n) -> float {
        float zs = (col < n) ? A.z : 0.0f;
        zs += (16 + col < n) ? B.z : 0.0f;
        zs = dpp_ror_add<0x128>(zs);   // row_ror:8
        zs = dpp_ror_add<0x124>(zs);   // row_ror:4
        zs = dpp_ror_add<0x122>(zs);   // row_ror:2
        zs = dpp_ror_add<0x121>(zs);   // row_ror:1
        return zs * fast_rcp(fmaxf((float)n, 1.0f));
    };

    const int nw = gridDim.x * WPB;
    const int npairs = (P + 1) >> 1;
    int pr = __builtin_amdgcn_readfirstlane(blockIdx.x * WPB + wave);
    if (pr >= npairs) return;

    // ---- preamble: load pair 0 ----
    int p0 = pr * 2;
    {
        // nothing
    }
    const float4* pb0 = (const float4*)(pillars + (size_t)p0 * 128);
    const int p1c = (p0 + 1 < P) ? p0 + 1 : P - 1;
    const float4* pb1 = (const float4*)(pillars + (size_t)p1c * 128);
    float4 ptA0 = pb0[col],      ptB0 = pb0[16 + col];
    float4 ptA1 = pb1[col],      ptB1 = pb1[16 + col];
    int np0 = npts_arr[p0];
    int np1 = (p0 + 1 < P) ? npts_arr[p0 + 1] : 0;
    int cy0 = coords[2 * p0],  cx0 = coords[2 * p0 + 1];
    int cy1 = coords[2 * p1c], cx1 = coords[2 * p1c + 1];
    np0 = np0 < 0 ? 0 : (np0 > 32 ? 32 : np0);
    np1 = np1 < 0 ? 0 : (np1 > 32 ? 32 : np1);
    float z0 = zreduce(ptA0, ptB0, np0);
    float z1 = zreduce(ptA1, ptB1, np1);

    while (true) {
        const int prn = pr + nw;
        const bool has_next = prn < npairs;
        float4 nA0, nB0, nA1, nB1;
        int nnp0 = 0, nnp1 = 0, ncy0 = 0, ncx0 = 0, ncy1 = 0, ncx1 = 0;
        if (has_next) {                       // wave-uniform; issue loads early
            const int q0 = prn * 2;
            const int q1c = (q0 + 1 < P) ? q0 + 1 : P - 1;
            const float4* qb0 = (const float4*)(pillars + (size_t)q0 * 128);
            const float4* qb1 = (const float4*)(pillars + (size_t)q1c * 128);
            nA0 = qb0[col];  nB0 = qb0[16 + col];
            nA1 = qb1[col];  nB1 = qb1[16 + col];
            nnp0 = npts_arr[q0];
            nnp1 = (q0 + 1 < P) ? npts_arr[q0 + 1] : 0;
            ncy0 = coords[2 * q0];  ncx0 = coords[2 * q0 + 1];
            ncy1 = coords[2 * q1c]; ncx1 = coords[2 * q1c + 1];
        }

        const int u0 = __builtin_amdgcn_readfirstlane(np0);
        const int u1 = __builtin_amdgcn_readfirstlane(np1);
        const int um = u0 > u1 ? u0 : u1;
        const float xc0f = ((float)cx0 + 0.5f) * RES_ + XMIN_;
        const float yc0f = ((float)cy0 + 0.5f) * RES_ + YMIN_;
        const float xc1f = ((float)cx1 + 0.5f) * RES_ + XMIN_;
        const float yc1f = ((float)cy1 + 0.5f) * RES_ + YMIN_;
        const float zm0 = z0, zm1 = z1;

        // ---- feat^T B-frag pack (per pillar, per half-tile) ----
        auto packB = [&](const float4& pt, float xcv, float ycv, float zmv) -> f16x4 {
            const float xo = pt.x - xcv;
            const float yo = pt.y - ycv;
            const f16x2 c01 = pkrtz(pt.x, pt.y);
            const f16x2 c23 = pkrtz(pt.z, pt.w);
            const f16x2 c45 = pkrtz(xo, yo);
            const f16x2 c67 = pkrtz(pt.z, xo);
            const f16x2 c89 = pkrtz(yo, 1.0f);
            const f16x2 cab = pkrtz(-zmv, 0.0f);
            const f16x2 z2  = (f16x2)(_Float16)0.f;
            F4u u;
            u.h[0] = (quad == 0) ? c01 : (quad == 1) ? c45 : (quad == 2) ? c89 : z2;
            u.h[1] = (quad == 0) ? c23 : (quad == 1) ? c67 : (quad == 2) ? cab : z2;
            return u.v;
        };
        auto repack = [&](const f32x4* a, f16x8* v) {
#pragma unroll
            for (int kt = 0; kt < 2; ++kt) {
                F8u w;
                w.h[0] = relu2(pkrtz(a[2 * kt][0],     a[2 * kt][1]));
                w.h[1] = relu2(pkrtz(a[2 * kt][2],     a[2 * kt][3]));
                w.h[2] = relu2(pkrtz(a[2 * kt + 1][0], a[2 * kt + 1][1]));
                w.h[3] = relu2(pkrtz(a[2 * kt + 1][2], a[2 * kt + 1][3]));
                v[kt] = w.v;
            }
        };

        float res0 = NEG_, res1 = NEG_;

        // ============ pair body: two interleaved independent chains ============
        auto body2 = [&](auto MTC) {
            constexpr int MT = decltype(MTC)::value;
            float h0[4] = {NEG_, NEG_, NEG_, NEG_};
            float h1[4] = {NEG_, NEG_, NEG_, NEG_};

#pragma unroll
            for (int t = 0; t < MT; ++t) {
                const float4 q0 = (t == 0) ? ptA0 : ptB0;
                const float4 q1 = (t == 0) ? ptA1 : ptB1;
                const f16x4 bt0 = packB(q0, xc0f, yc0f, zm0);
                const f16x4 bt1 = packB(q1, xc1f, yc1f, zm1);

                // layer-1: 8 independent MFMAs back-to-back (fills MFMA pipe)
                f32x4 a0[4], a1[4];
                const f32x4 zz = {0.f, 0.f, 0.f, 0.f};
#pragma unroll
                for (int mt = 0; mt < 4; ++mt) {
                    a0[mt] = __builtin_amdgcn_mfma_f32_16x16x16f16(aw1[mt], bt0, zz, 0, 0, 0);
                    a1[mt] = __builtin_amdgcn_mfma_f32_16x16x16f16(aw1[mt], bt1, zz, 0, 0, 0);
                }

                // repack both (independent VALU chains)
                f16x8 v0[2], v1[2];
                repack(a0, v0);
                repack(a1, v1);

                // row-mask C-init for both
                f32x4 cm0, cm1;
#pragma unroll
                for (int r = 0; r < 4; ++r) {
                    const int row = t * 16 + quad * 4 + r;
                    cm0[r] = (row < np0) ? 0.0f : NEG_;
                    cm1[r] = (row < np1) ? 0.0f : NEG_;
                }

                // layer-2: paired streams per nt
#pragma unroll
                for (int nt = 0; nt < 4; ++nt) {
                    f32x4 x0 = __builtin_amdgcn_mfma_f32_16x16x32_f16(v0[0], bw2[0][nt], cm0, 0, 0, 0);
                    f32x4 x1 = __builtin_amdgcn_mfma_f32_16x16x32_f16(v1[0], bw2[0][nt], cm1, 0, 0, 0);
                    x0 = __builtin_amdgcn_mfma_f32_16x16x32_f16(v0[1], bw2[1][nt], x0, 0, 0, 0);
                    x1 = __builtin_amdgcn_mfma_f32_16x16x32_f16(v1[1], bw2[1][nt], x1, 0, 0, 0);
                    h0[nt] = fmaxf(fmaxf(h0[nt], fmaxf(x0[0], x0[1])), fmaxf(x0[2], x0[3]));
                    h1[nt] = fmaxf(fmaxf(h1[nt], fmaxf(x1[0], x1[1])), fmaxf(x1[2], x1[3]));
                }
            }

            // epilogue: dual permlane chains (independent)
            float e0[4], e1[4];
#pragma unroll
            for (int nt = 0; nt < 4; ++nt) {
                e0[nt] = xmax32(xmax16(h0[nt]));
                e1[nt] = xmax32(xmax16(h1[nt]));
            }
            const float s0 = (quad == 0) ? e0[0] : (quad == 1) ? e0[1] : (quad == 2) ? e0[2] : e0[3];
            const float s1 = (quad == 0) ? e1[0] : (quad == 1) ? e1[1] : (quad == 2) ? e1[2] : e1[3];
            res0 = fmaxf(s0 + c2own, 0.0f);
            res1 = fmaxf(s1 + c2own, 0.0f);
        };

        if (um > 16)     body2(std::integral_constant<int, 2>{});
        else if (um > 0) body2(std::integral_constant<int, 1>{});
        // um == 0: both empty, res stay NEG_

        // per-pillar np==0 override (reference: empty pillar -> NEG, no relu)
        out[(size_t)p0 * 64 + lane] = (u0 > 0) ? res0 : NEG_;
        if (p0 + 1 < P)
            out[(size_t)(p0 + 1) * 64 + lane] = (u1 > 0) ? res1 : NEG_;

        if (!has_next) break;

        // z for NEXT pair (two independent DPP chains)
        nnp0 = nnp0 < 0 ? 0 : (nnp0 > 32 ? 32 : nnp0);
        nnp1 = nnp1 < 0 ? 0 : (nnp1 > 32 ? 32 : nnp1);
        z0 = zreduce(nA0, nB0, nnp0);
        z1 = zreduce(nA1, nB1, nnp1);

        pr = prn; p0 = prn * 2;
        ptA0 = nA0; ptB0 = nB0; ptA1 = nA1; ptB1 = nB1;
        np0 = nnp0; np1 = nnp1;
        cy0 = ncy0; cx0 = ncx0; cy1 = ncy1; cx1 = ncx1;
    }
}

extern "C" void kernel_launch(void* const* d_in, const int* in_sizes, int n_in,
                              void* d_out, int out_size, void* d_ws, size_t ws_size,
                              hipStream_t stream) {
    const float* pillars = (const float*)d_in[0];
    const int*   coords  = (const int*)d_in[1];
    const int*   npts    = (const int*)d_in[2];
    const float* W1      = (const float*)d_in[3];
    const float* b1      = (const float*)d_in[4];
    const float* g1      = (const float*)d_in[5];
    const float* beta1   = (const float*)d_in[6];
    const float* m1      = (const float*)d_in[7];
    const float* v1      = (const float*)d_in[8];
    const float* W2      = (const float*)d_in[9];
    const float* b2      = (const float*)d_in[10];
    const float* g2      = (const float*)d_in[11];
    const float* beta2   = (const float*)d_in[12];
    const float* m2      = (const float*)d_in[13];
    const float* v2      = (const float*)d_in[14];
    float* out           = (float*)d_out;

    const int P = in_sizes[2];
    // 1024 blocks; residency self-limits (3-4 blocks/CU at ~150 unified regs).
    const int blocks = 1024;

    hipLaunchKernelGGL(pfn_kernel, dim3(blocks), dim3(256), 0, stream,
                       pillars, coords, npts, W1, b1, g1, beta1, m1, v1,
                       W2, b2, g2, beta2, m2, v2, out, P);
}

// Round 7
// 154.303 us; speedup vs baseline: 1.0832x; 1.0832x over previous
//
#include <hip/hip_runtime.h>
#include <type_traits>

#define RES_ 0.16f
#define XMIN_ -51.2f
#define YMIN_ -51.2f
#define EPS_ 1e-5f
#define NEG_ -1000000000.0f

#define WPB 4  // waves per block

typedef _Float16 f16x8 __attribute__((ext_vector_type(8)));
typedef _Float16 f16x4 __attribute__((ext_vector_type(4)));
typedef _Float16 f16x2 __attribute__((ext_vector_type(2)));
typedef float f32x4 __attribute__((ext_vector_type(4)));

union F8u { f16x8 v; f16x2 h[4]; };
union F4u { f16x4 v; f16x2 h[2]; };

static __device__ __forceinline__ f16x2 pkrtz(float a, float b) {
    return __builtin_bit_cast(f16x2, __builtin_amdgcn_cvt_pkrtz(a, b));
}

static __device__ __forceinline__ f16x2 relu2(f16x2 x) {
#if __has_builtin(__builtin_elementwise_max)
    const f16x2 z2 = (f16x2)(_Float16)0.f;
    return __builtin_elementwise_max(x, z2);   // v_pk_max_f16
#else
    f16x2 r;
    r[0] = x[0] > (_Float16)0.f ? x[0] : (_Float16)0.f;
    r[1] = x[1] > (_Float16)0.f ? x[1] : (_Float16)0.f;
    return r;
#endif
}

static __device__ __forceinline__ float fast_rcp(float x) {
#if __has_builtin(__builtin_amdgcn_rcpf)
    return __builtin_amdgcn_rcpf(x);
#else
    return 1.0f / x;
#endif
}

// DPP row_ror add — pure-VALU cross-lane sum within each 16-lane row.
template <int CTRL>
static __device__ __forceinline__ float dpp_ror_add(float x) {
    int r = __builtin_amdgcn_update_dpp(0, __float_as_int(x), CTRL, 0xf, 0xf, true);
    return x + __int_as_float(r);
}

// xor16 / xor32 max via gfx950 VALU cross-lane swaps (zero DS traffic).
static __device__ __forceinline__ float xmax16(float x) {
    float a = x, b = x;
    asm("v_permlane16_swap_b32 %0, %1" : "+v"(a), "+v"(b));
    return fmaxf(a, b);
}
static __device__ __forceinline__ float xmax32(float x) {
    float a = x, b = x;
    asm("v_permlane32_swap_b32 %0, %1" : "+v"(a), "+v"(b));
    return fmaxf(a, b);
}

// r19: two b128 LDS reads + wait, as ONE volatile asm block.
// volatile => LICM cannot hoist the 8 reads out of the pillar loop (which
// would re-create the 32-reg bw2 footprint we just freed). The consuming
// MFMAs take the asm OUTPUTS as operands -> true data dependency -> they
// cannot be scheduled above the lgkmcnt(0) (rule-18 safe).
template <int IDX0, int IDX1>
static __device__ __forceinline__ void lds_read2_b128(unsigned base, f16x8& a, f16x8& b) {
    asm volatile("ds_read_b128 %0, %2 offset:%c3\n\t"
                 "ds_read_b128 %1, %2 offset:%c4\n\t"
                 "s_waitcnt lgkmcnt(0)"
                 : "=v"(a), "=v"(b)
                 : "v"(base), "i"(IDX0 * 1024), "i"(IDX1 * 1024));
}

// NOTE (r11): zero-LDS dataflow — layer-1 transposed (W1^T @ feat^T); its MFMA
// C-output IS layer-2's A-operand under W2 k-row perm c=32kt+16(j>>2)+4q+(j&3).
// NOTE (occupancy model, r14/r15/r18): the compiler allocates TO the
// launch_bounds budget (VGPR_Count is arch-only; unified file incl. acc is
// what caps residency). (256,4)->4 waves/SIMD, (256,3)->3 (r18, 23% occ,
// slower), (256,8)->budget 64 << demand -> spill (r14). Occupancy is
// budget-set; to raise it, REDUCE DEMAND then tighten the bound.
// NOTE (r18 PIN): pillar-pairing ILP regressed (VGPR 76, 3 waves/SIMD,
// 74us, absmax 70.5). Do not retry.
// NOTE (r19): bw2 (32 regs, wave-invariant) -> LDS (8KB),
// computed cooperatively (wave w owns nt=w slice, barrier), read per-nt as
// 2x ds_read_b128 via volatile asm. Demand ~120 -> ~88; launch_bounds
// (256,5) budget=102 now fits -> 5 waves/SIMD. The old "(256,5) spills"
// pin (r9/r12) predates the -32-reg change; retested deliberately.
// Tripwires: WRITE_SIZE==25000KB, absmax==0.5, SQ_LDS_BANK_CONFLICT small.
// NOTE (r20): round 6 bench was an infra failure (container died twice);
// this is an UNCHANGED resubmit of r19 — do not read round-6 as evidence.
// NOTE (r16/r17): all cross-lane on VALU (DPP ror-add, permlane swaps) —
// neutral vs shuffles but cheaper; kept.
__global__ __launch_bounds__(256, 5) void pfn_kernel(
    const float* __restrict__ pillars,
    const int* __restrict__ coords,
    const int* __restrict__ npts_arr,
    const float* __restrict__ W1, const float* __restrict__ b1,
    const float* __restrict__ g1, const float* __restrict__ beta1,
    const float* __restrict__ m1, const float* __restrict__ v1,
    const float* __restrict__ W2, const float* __restrict__ b2,
    const float* __restrict__ g2, const float* __restrict__ beta2,
    const float* __restrict__ m2, const float* __restrict__ v2,
    float* __restrict__ out, int P)
{
    const int tid  = threadIdx.x;
    const int wave = tid >> 6;
    const int lane = tid & 63;
    const int quad = lane >> 4;
    const int col  = lane & 15;

    // [kt*4+nt][lane][8 halfs] — 8KB. Identical for all waves/blocks.
    __shared__ _Float16 bw2s[8][64][8];

    // ---- cooperative bw2 preamble: wave w computes nt=w slice (kt=0,1) ----
    {
        const int nt = wave;
        const int n0 = nt * 16 + col;
        const float a2 = g2[n0] * rsqrtf(v2[n0] + EPS_);
#pragma unroll
        for (int kt = 0; kt < 2; ++kt) {
            F8u w;
#pragma unroll
            for (int j = 0; j < 8; ++j) {
                const int c = 32 * kt + 16 * (j >> 2) + 4 * quad + (j & 3);
                w.v[j] = (_Float16)(a2 * W2[c * 64 + n0]);
            }
            *(f16x8*)&bw2s[kt * 4 + nt][lane][0] = w.v;
        }
    }

    // ---- W1^T as layer-1 A-frags (K padded 9->16), BN1 folded (per wave) ----
    f16x4 aw1[4];
#pragma unroll
    for (int mt = 0; mt < 4; ++mt) {
        const int ch = mt * 16 + col;
        const float a1 = g1[ch] * rsqrtf(v1[ch] + EPS_);
        const float c1 = fmaf(a1, b1[ch] - m1[ch], beta1[ch]);
#pragma unroll
        for (int j = 0; j < 4; ++j) {
            const int k = quad * 4 + j;
            float w;
            if (k < 9)        w = a1 * W1[k * 64 + ch];
            else if (k == 9)  w = c1;                      // bias slot (feat=1.0)
            else if (k == 10) w = a1 * W1[6 * 64 + ch];    // z_mean slot (feat=-zm)
            else              w = 0.0f;
            aw1[mt][j] = (_Float16)w;
        }
    }
    const float c2own = fmaf(g2[lane] * rsqrtf(v2[lane] + EPS_),
                             b2[lane] - m2[lane], beta2[lane]);

    __syncthreads();   // bw2s ready (must precede any return)

    const unsigned bwbase = (unsigned)(size_t)&bw2s[0][lane][0];

    auto zreduce = [&](const float4& A, const float4& B, int n) -> float {
        float zs = (col < n) ? A.z : 0.0f;
        zs += (16 + col < n) ? B.z : 0.0f;
        zs = dpp_ror_add<0x128>(zs);   // row_ror:8
        zs = dpp_ror_add<0x124>(zs);   // row_ror:4
        zs = dpp_ror_add<0x122>(zs);   // row_ror:2
        zs = dpp_ror_add<0x121>(zs);   // row_ror:1
        return zs * fast_rcp(fmaxf((float)n, 1.0f));
    };

    const int nwaves = gridDim.x * WPB;
    int p = __builtin_amdgcn_readfirstlane(blockIdx.x * WPB + wave);
    if (p >= P) return;

    // ---- preamble: load + z for pillar 0 ----
    const float4* pb = (const float4*)(pillars + (size_t)p * 128);
    float4 ptA = pb[col];
    float4 ptB = pb[16 + col];
    int np = npts_arr[p];
    int cy = coords[2 * p], cx = coords[2 * p + 1];
    np = np < 0 ? 0 : (np > 32 ? 32 : np);
    float z_cur = zreduce(ptA, ptB, np);

    while (true) {
        const int pn = p + nwaves;
        const bool has_next = pn < P;
        float4 ptAn, ptBn; int npn = 0, cyn = 0, cxn = 0;
        if (has_next) {                       // wave-uniform; issue loads early
            const float4* pbn = (const float4*)(pillars + (size_t)pn * 128);
            ptAn = pbn[col];
            ptBn = pbn[16 + col];
            npn = npts_arr[pn];
            cyn = coords[2 * pn]; cxn = coords[2 * pn + 1];
        }

        const int npu = __builtin_amdgcn_readfirstlane(np);
        const float xc = ((float)cx + 0.5f) * RES_ + XMIN_;
        const float yc = ((float)cy + 0.5f) * RES_ + YMIN_;
        const float z_mean = z_cur;

        // ================= pillar body (zero global-LDS traffic beyond bw2s) ==
        auto body = [&](auto MTC) -> float {
            constexpr int MT = decltype(MTC)::value;
            float hm4[4] = {NEG_, NEG_, NEG_, NEG_};

#pragma unroll
            for (int t = 0; t < MT; ++t) {
                const float4 pt = (t == 0) ? ptA : ptB;

                // ---- feat^T B-frag: B[k=quad*4+j][n=point col] ----
                const float xo = pt.x - xc;
                const float yo = pt.y - yc;
                const f16x2 c01 = pkrtz(pt.x, pt.y);       // quad0: x,y
                const f16x2 c23 = pkrtz(pt.z, pt.w);       // quad0: z,r
                const f16x2 c45 = pkrtz(xo, yo);           // quad1: xo,yo
                const f16x2 c67 = pkrtz(pt.z, xo);         // quad1: z(slot6), xo
                const f16x2 c89 = pkrtz(yo, 1.0f);         // quad2: yo, bias-1
                const f16x2 cab = pkrtz(-z_mean, 0.0f);    // quad2: -zm, 0
                const f16x2 z2  = (f16x2)(_Float16)0.f;
                F4u u;
                u.h[0] = (quad == 0) ? c01 : (quad == 1) ? c45 : (quad == 2) ? c89 : z2;
                u.h[1] = (quad == 0) ? c23 : (quad == 1) ? c67 : (quad == 2) ? cab : z2;
                const f16x4 bt = u.v;

                // ---- layer-1: 4 MFMAs, C=0 (bias+z in K-slots) ----
                f32x4 acc1[4];
                const f32x4 zz = {0.f, 0.f, 0.f, 0.f};
#pragma unroll
                for (int mt = 0; mt < 4; ++mt)
                    acc1[mt] = __builtin_amdgcn_mfma_f32_16x16x16f16(aw1[mt], bt, zz, 0, 0, 0);

                // ---- h1 relu + pack: layer-2 A-frags, pure in-lane ----
                f16x8 av2[2];
#pragma unroll
                for (int kt = 0; kt < 2; ++kt) {
                    F8u w;
                    w.h[0] = relu2(pkrtz(acc1[2 * kt][0],     acc1[2 * kt][1]));
                    w.h[1] = relu2(pkrtz(acc1[2 * kt][2],     acc1[2 * kt][3]));
                    w.h[2] = relu2(pkrtz(acc1[2 * kt + 1][0], acc1[2 * kt + 1][1]));
                    w.h[3] = relu2(pkrtz(acc1[2 * kt + 1][2], acc1[2 * kt + 1][3]));
                    av2[kt] = w.v;
                }

                // ---- row-mask as layer-2 C-init (free adds) ----
                f32x4 cm;
#pragma unroll
                for (int r = 0; r < 4; ++r)
                    cm[r] = (t * 16 + quad * 4 + r < np) ? 0.0f : NEG_;

                // ---- layer-2: stream per nt; bw2 frags from LDS ----
                auto nts = [&](auto NTC) {
                    constexpr int nt = decltype(NTC)::value;
                    f16x8 b0, b1;
                    lds_read2_b128<nt, 4 + nt>(bwbase, b0, b1);
                    f32x4 acc = __builtin_amdgcn_mfma_f32_16x16x32_f16(av2[0], b0, cm, 0, 0, 0);
                    acc = __builtin_amdgcn_mfma_f32_16x16x32_f16(av2[1], b1, acc, 0, 0, 0);
                    hm4[nt] = fmaxf(fmaxf(hm4[nt], fmaxf(acc[0], acc[1])),
                                    fmaxf(acc[2], acc[3]));
                };
                nts(std::integral_constant<int, 0>{});
                nts(std::integral_constant<int, 1>{});
                nts(std::integral_constant<int, 2>{});
                nts(std::integral_constant<int, 3>{});
            }

            // ---- cross-quad max via permlane swaps (VALU, no DS) ----
            float hmv[4];
#pragma unroll
            for (int nt = 0; nt < 4; ++nt)
                hmv[nt] = xmax32(xmax16(hm4[nt]));
            float r0 = (quad == 0) ? hmv[0] : (quad == 1) ? hmv[1] : (quad == 2) ? hmv[2] : hmv[3];
            return fmaxf(r0 + c2own, 0.0f);
        };

        float res;
        if (npu > 16)     res = body(std::integral_constant<int, 2>{});
        else if (npu > 0) res = body(std::integral_constant<int, 1>{});
        else              res = NEG_;
        out[(size_t)p * 64 + lane] = res;

        if (!has_next) break;

        // ---- pipelined: z for NEXT pillar (pure VALU) ----
        npn = npn < 0 ? 0 : (npn > 32 ? 32 : npn);
        z_cur = zreduce(ptAn, ptBn, npn);

        p = pn; ptA = ptAn; ptB = ptBn; np = npn; cy = cyn; cx = cxn;
    }
}

extern "C" void kernel_launch(void* const* d_in, const int* in_sizes, int n_in,
                              void* d_out, int out_size, void* d_ws, size_t ws_size,
                              hipStream_t stream) {
    const float* pillars = (const float*)d_in[0];
    const int*   coords  = (const int*)d_in[1];
    const int*   npts    = (const int*)d_in[2];
    const float* W1      = (const float*)d_in[3];
    const float* b1      = (const float*)d_in[4];
    const float* g1      = (const float*)d_in[5];
    const float* beta1   = (const float*)d_in[6];
    const float* m1      = (const float*)d_in[7];
    const float* v1      = (const float*)d_in[8];
    const float* W2      = (const float*)d_in[9];
    const float* b2      = (const float*)d_in[10];
    const float* g2      = (const float*)d_in[11];
    const float* beta2   = (const float*)d_in[12];
    const float* m2      = (const float*)d_in[13];
    const float* v2      = (const float*)d_in[14];
    float* out           = (float*)d_out;

    const int P = in_sizes[2];
    // r19: 1280 blocks = 5 blocks/CU at 5 waves/SIMD (launch_bounds (256,5),
    // budget 102 regs, demand ~88 after bw2->LDS). LDS 8448B/block -> not
    // the residency limiter.
    const int blocks = 1280;

    hipLaunchKernelGGL(pfn_kernel, dim3(blocks), dim3(256), 0, stream,
                       pillars, coords, npts, W1, b1, g1, beta1, m1, v1,
                       W2, b2, g2, beta2, m2, v2, out, P);
}